// Round 4
// baseline (287.847 us; speedup 1.0000x reference)
//
#include <hip/hip_runtime.h>
#include <hip/hip_bf16.h>

// ---------- common ----------
typedef __bf16 bf16x8 __attribute__((ext_vector_type(8)));
typedef float  f32x4  __attribute__((ext_vector_type(4)));

#define GLOAD_LDS16(g, l) \
  __builtin_amdgcn_global_load_lds((const __attribute__((address_space(1))) void*)(g), \
                                   (__attribute__((address_space(3))) void*)(l), 16, 0, 0)

static __device__ __forceinline__ ushort f2bf(float f) {
  union { float f; unsigned u; } x; x.f = f;
  unsigned r = x.u + 0x7fffu + ((x.u >> 16) & 1u);   // RNE
  return (ushort)(r >> 16);
}
static __device__ __forceinline__ float bf2f(ushort u) {
  union { unsigned u; float f; } x; x.u = ((unsigned)u) << 16;
  return x.f;
}

// ---------- kernel 1: cast x fp32 -> bf16 ----------
__global__ void cast_x_k(const float4* __restrict__ in, ushort4* __restrict__ out, int n4) {
  int idx = blockIdx.x * 256 + threadIdx.x;
  int stride = gridDim.x * 256;
  for (int i = idx; i < n4; i += stride) {
    float4 v = in[i];
    ushort4 o;
    o.x = f2bf(v.x); o.y = f2bf(v.y); o.z = f2bf(v.z); o.w = f2bf(v.w);
    out[i] = o;
  }
}

// ---------- kernel 2: pack 6 weights into Wt[1536][2048] bf16 (transposed, zero-padded) ----
// column map: 0-95 a_q | 96-111 a_k | 112-127 a_v | 128-895 b_q | 896-1151 b_k
//             | 1152-1407 b_v | 1408-1535 zero pad
__global__ void pack_wt_k(const float* __restrict__ W0, const float* __restrict__ W1,
                          const float* __restrict__ W2, const float* __restrict__ W3,
                          const float* __restrict__ W4, const float* __restrict__ W5,
                          ushort* __restrict__ Wt) {
  __shared__ ushort tile[64 * 66];
  const int k0 = blockIdx.x * 64, c0 = blockIdx.y * 64;
  const int tid = threadIdx.x;
#pragma unroll
  for (int i = 0; i < 16; ++i) {
    int idx = tid + i * 256;
    int kl = idx >> 6, cl = idx & 63;
    int c = c0 + cl, k = k0 + kl;
    float v;
    if (c < 96)        v = W0[(size_t)k * 96  + c];
    else if (c < 112)  v = W1[(size_t)k * 16  + (c - 96)];
    else if (c < 128)  v = W2[(size_t)k * 16  + (c - 112)];
    else if (c < 896)  v = W3[(size_t)k * 768 + (c - 128)];
    else if (c < 1152) v = W4[(size_t)k * 256 + (c - 896)];
    else if (c < 1408) v = W5[(size_t)k * 256 + (c - 1152)];
    else               v = 0.0f;
    tile[cl * 66 + kl] = f2bf(v);
  }
  __syncthreads();
#pragma unroll
  for (int i = 0; i < 16; ++i) {
    int idx = tid + i * 256;
    int cl = idx >> 6, kl = idx & 63;
    Wt[(size_t)(c0 + cl) * 2048 + (k0 + kl)] = tile[cl * 66 + kl];
  }
}

// ---------- kernel 3: GEMM  Y[8192][1536] = Xbf[8192][2048] @ Wt[1536][2048]^T, bf16 out ----
// 256x256 tile, 512 threads (8 waves, 2x4), BK=32, 4 LDS buffers (128 KB),
// 2 phases per K-tile (16 MFMA each, B frags register-cached), staging 3 tiles ahead,
// boundary s_waitcnt vmcnt(8) (never 0 until the tail).  Race-free by construction:
// tile t+3's buffer ((t+3)&3 == (t-1)&3) was fully read before tile t began.
__global__ __launch_bounds__(512, 2) void gemm_bt_k(const ushort* __restrict__ X,
                                                    const ushort* __restrict__ Wt,
                                                    ushort* __restrict__ Y) {
  extern __shared__ ushort lds[];                 // 4 bufs x 16384 elems (32 KB each)
  const int tid = threadIdx.x;
  const int wid = tid >> 6, lane = tid & 63;
  const int bid = blockIdx.x;
  const int wg = (bid & 7) * 24 + (bid >> 3);     // XCD-chunked swizzle, 192 = 8*24
  const int bm = wg & 31, bn = wg >> 5;           // 32 x 6 tiles
  const int wr = wid >> 2, wc = wid & 3;          // wave -> (row-half, col-quarter)

  // ---- staging geometry: per K-tile 4 gload insts (A0,A1,B0,B1), 8 KB each ----
  const int srow0 = wid * 16 + (lane >> 2);       // inst j=0: rows 0-127
  const int srow1 = 128 + srow0;                  // inst j=1: rows 128-255
  const int g0 = (lane & 3) ^ ((srow0 >> 1) & 3); // pre-swizzled source chunk
  const int g1 = (lane & 3) ^ ((srow1 >> 1) & 3);
  const ushort* gA0 = X  + (size_t)(bm * 256 + srow0) * 2048 + g0 * 8;
  const ushort* gA1 = X  + (size_t)(bm * 256 + srow1) * 2048 + g1 * 8;
  const ushort* gB0 = Wt + (size_t)(bn * 256 + srow0) * 2048 + g0 * 8;
  const ushort* gB1 = Wt + (size_t)(bn * 256 + srow1) * 2048 + g1 * 8;
  const int sA0 = wid * 1024, sA1 = 8192 + wid * 1024;      // LDS byte bases (wave-uniform)
  const int sB0 = 16384 + wid * 1024, sB1 = 24576 + wid * 1024;

  // ---- fragment ds_read offsets (ushort units), swizzle-matched ----
  int offA[8], offB[4];
#pragma unroll
  for (int m = 0; m < 8; ++m) {
    int ra = wr * 128 + m * 16 + (lane & 15);
    int s = (lane >> 4) ^ ((ra >> 1) & 3);
    offA[m] = ra * 32 + s * 8;
  }
#pragma unroll
  for (int n = 0; n < 4; ++n) {
    int cb = wc * 64 + n * 16 + (lane & 15);
    int s = (lane >> 4) ^ ((cb >> 1) & 3);
    offB[n] = 8192 + cb * 32 + s * 8;
  }

#define STAGEA(bi, kt) do { char* _s = (char*)lds + (bi) * 32768; const int _ko = (kt) * 32; \
    GLOAD_LDS16(gA0 + _ko, _s + sA0); GLOAD_LDS16(gA1 + _ko, _s + sA1); } while (0)
#define STAGEB(bi, kt) do { char* _s = (char*)lds + (bi) * 32768; const int _ko = (kt) * 32; \
    GLOAD_LDS16(gB0 + _ko, _s + sB0); GLOAD_LDS16(gB1 + _ko, _s + sB1); } while (0)
#define FRAG(base, off) (*reinterpret_cast<const bf16x8*>((base) + (off)))
#define BARM() asm volatile("s_barrier" ::: "memory")
#define MF(mi, av) { \
    acc[mi][0] = __builtin_amdgcn_mfma_f32_16x16x32_bf16(av, bq0, acc[mi][0], 0, 0, 0); \
    acc[mi][1] = __builtin_amdgcn_mfma_f32_16x16x32_bf16(av, bq1, acc[mi][1], 0, 0, 0); \
    acc[mi][2] = __builtin_amdgcn_mfma_f32_16x16x32_bf16(av, bq2, acc[mi][2], 0, 0, 0); \
    acc[mi][3] = __builtin_amdgcn_mfma_f32_16x16x32_bf16(av, bq3, acc[mi][3], 0, 0, 0); }

  f32x4 acc[8][4] = {};

  // prologue: stage K-tiles 0,1,2 into bufs 0,1,2 (12 insts in flight)
  STAGEA(0, 0); STAGEB(0, 0);
  STAGEA(1, 1); STAGEB(1, 1);
  STAGEA(2, 2); STAGEB(2, 2);

#pragma unroll 1
  for (int t = 0; t < 64; ++t) {
    const ushort* cbuf = lds + (t & 3) * 16384;
    const int nb = (t + 3) & 3;
    // boundary: retire tile t's staging (keep t+1, t+2 in flight)
    if (t <= 61)      asm volatile("s_waitcnt vmcnt(8)" ::: "memory");
    else if (t == 62) asm volatile("s_waitcnt vmcnt(4)" ::: "memory");
    else              asm volatile("s_waitcnt vmcnt(0)" ::: "memory");
    BARM();

    // ---- phase 1: frags m0-3 + all B; stage A halves of tile t+3 ----
    bf16x8 af0 = FRAG(cbuf, offA[0]), af1 = FRAG(cbuf, offA[1]),
           af2 = FRAG(cbuf, offA[2]), af3 = FRAG(cbuf, offA[3]);
    bf16x8 bq0 = FRAG(cbuf, offB[0]), bq1 = FRAG(cbuf, offB[1]),
           bq2 = FRAG(cbuf, offB[2]), bq3 = FRAG(cbuf, offB[3]);
    if (t <= 60) STAGEA(nb, t + 3);
    BARM();
    __builtin_amdgcn_sched_barrier(0);
    __builtin_amdgcn_s_setprio(1);
    MF(0, af0) MF(1, af1) MF(2, af2) MF(3, af3)
    __builtin_amdgcn_s_setprio(0);
    BARM();

    // ---- phase 2: frags m4-7; stage B halves of tile t+3 ----
    af0 = FRAG(cbuf, offA[4]); af1 = FRAG(cbuf, offA[5]);
    af2 = FRAG(cbuf, offA[6]); af3 = FRAG(cbuf, offA[7]);
    if (t <= 60) STAGEB(nb, t + 3);
    BARM();
    __builtin_amdgcn_sched_barrier(0);
    __builtin_amdgcn_s_setprio(1);
    MF(4, af0) MF(5, af1) MF(6, af2) MF(7, af3)
    __builtin_amdgcn_s_setprio(0);
    BARM();
  }

#undef STAGEA
#undef STAGEB
#undef FRAG
#undef BARM
#undef MF

  // epilogue: C/D layout col=lane&15, row=(lane>>4)*4+j  [m89-verified]; bf16 stores
#pragma unroll
  for (int m = 0; m < 8; ++m) {
    int row0 = bm * 256 + wr * 128 + m * 16 + ((lane >> 4) << 2);
#pragma unroll
    for (int n = 0; n < 4; ++n) {
      int col = bn * 256 + wc * 64 + n * 16 + (lane & 15);
#pragma unroll
      for (int j = 0; j < 4; ++j)
        Y[(size_t)(row0 + j) * 1536 + col] = f2bf(acc[m][n][j]);
    }
  }
}

// ---------- kernel 4: per-token low-rank reconstruction + concat (bf16 Y in, f32 out) ----
// Y row (stride 1536, first 1408 valid): [0,96) a_q | [96,112) a_k | [112,128) a_v
//   | [128,896) b_q | [896,1152) b_k | [1152,1408) b_v
// out row (4096): per group g: q_head(2g)[128] q_head(2g+1)[128] k_g[128] v_g[128]
__global__ void recon_k(const ushort* __restrict__ Y, float4* __restrict__ out) {
  __shared__ float L[1408];
  const int t = blockIdx.x, tid = threadIdx.x;
  const ushort* src = Y + (size_t)t * 1536;
  if (tid < 176) {                        // 176 x 16B = 1408 bf16
    ushort4 v0 = ((const ushort4*)src)[tid * 2];
    ushort4 v1 = ((const ushort4*)src)[tid * 2 + 1];
    float* d = L + tid * 8;
    d[0] = bf2f(v0.x); d[1] = bf2f(v0.y); d[2] = bf2f(v0.z); d[3] = bf2f(v0.w);
    d[4] = bf2f(v1.x); d[5] = bf2f(v1.y); d[6] = bf2f(v1.z); d[7] = bf2f(v1.w);
  }
  __syncthreads();
  float4* o = out + (size_t)t * 1024;
#pragma unroll
  for (int i = 0; i < 4; ++i) {
    int q4 = tid + (i << 8);              // float4 index 0..1023
    int p = q4 << 2;
    int g = p >> 9, sub = p & 511;
    float4 val;
    if (sub < 256) {                      // q
      int h = (g << 1) + (sub >> 7), d = sub & 127;
      const float* a = L + h * 6;
      const float* b = L + 128 + d;
#pragma unroll
      for (int c = 0; c < 4; ++c)
        (&val.x)[c] = (a[0] * b[c] + a[1] * b[128 + c] + a[2] * b[256 + c] +
                       a[3] * b[384 + c] + a[4] * b[512 + c] + a[5] * b[640 + c]) * (1.0f / 6.0f);
    } else if (sub < 384) {               // k
      int d = sub - 256;
      float a0 = L[96 + (g << 1)], a1 = L[97 + (g << 1)];
#pragma unroll
      for (int c = 0; c < 4; ++c)
        (&val.x)[c] = 0.5f * (a0 * L[896 + d + c] + a1 * L[1024 + d + c]);
    } else {                              // v
      int d = sub - 384;
      float a0 = L[112 + (g << 1)], a1 = L[113 + (g << 1)];
#pragma unroll
      for (int c = 0; c < 4; ++c)
        (&val.x)[c] = 0.5f * (a0 * L[1152 + d + c] + a1 * L[1280 + d + c]);
    }
    o[q4] = val;
  }
}

// ---------- launch ----------
extern "C" void kernel_launch(void* const* d_in, const int* in_sizes, int n_in,
                              void* d_out, int out_size, void* d_ws, size_t ws_size,
                              hipStream_t stream) {
  const float* x   = (const float*)d_in[0];
  const float* Waq = (const float*)d_in[1];
  const float* Wak = (const float*)d_in[2];
  const float* Wav = (const float*)d_in[3];
  const float* Wbq = (const float*)d_in[4];
  const float* Wbk = (const float*)d_in[5];
  const float* Wbv = (const float*)d_in[6];

  // workspace layout
  ushort* Xbf = (ushort*)d_ws;                                  // 8192*2048*2 = 33,554,432 B
  ushort* Wt  = (ushort*)((char*)d_ws + 33554432);              // 1536*2048*2 =  6,291,456 B
  ushort* Y   = (ushort*)((char*)d_ws + 39845888);              // 8192*1536*2 = 25,165,824 B
  float*  out = (float*)d_out;

  // allow 128 KB dynamic LDS for the gemm (idempotent; same call every launch)
  hipFuncSetAttribute(reinterpret_cast<const void*>(gemm_bt_k),
                      hipFuncAttributeMaxDynamicSharedMemorySize, 131072);

  cast_x_k<<<2048, 256, 0, stream>>>((const float4*)x, (ushort4*)Xbf, 16777216 / 4);
  pack_wt_k<<<dim3(32, 24), 256, 0, stream>>>(Waq, Wak, Wav, Wbq, Wbk, Wbv, Wt);
  gemm_bt_k<<<192, 512, 131072, stream>>>(Xbf, Wt, Y);
  recon_k<<<8192, 256, 0, stream>>>(Y, (float4*)out);
}

// Round 5
// 277.186 us; speedup vs baseline: 1.0385x; 1.0385x over previous
//
#include <hip/hip_runtime.h>
#include <hip/hip_bf16.h>

// ---------- common ----------
typedef __bf16 bf16x8 __attribute__((ext_vector_type(8)));
typedef float  f32x4  __attribute__((ext_vector_type(4)));

#define GLOAD_LDS16(g, l) \
  __builtin_amdgcn_global_load_lds((const __attribute__((address_space(1))) void*)(g), \
                                   (__attribute__((address_space(3))) void*)(l), 16, 0, 0)

static __device__ __forceinline__ ushort f2bf(float f) {
  union { float f; unsigned u; } x; x.f = f;
  unsigned r = x.u + 0x7fffu + ((x.u >> 16) & 1u);   // RNE
  return (ushort)(r >> 16);
}
static __device__ __forceinline__ float bf2f(ushort u) {
  union { unsigned u; float f; } x; x.u = ((unsigned)u) << 16;
  return x.f;
}

// ---------- kernel 1: cast x fp32 -> bf16 ----------
__global__ void cast_x_k(const float4* __restrict__ in, ushort4* __restrict__ out, int n4) {
  int idx = blockIdx.x * 256 + threadIdx.x;
  int stride = gridDim.x * 256;
  for (int i = idx; i < n4; i += stride) {
    float4 v = in[i];
    ushort4 o;
    o.x = f2bf(v.x); o.y = f2bf(v.y); o.z = f2bf(v.z); o.w = f2bf(v.w);
    out[i] = o;
  }
}

// ---------- kernel 2: pack 6 weights into Wt[1536][2048] bf16 (transposed, zero-padded) ----
// column map: 0-95 a_q | 96-111 a_k | 112-127 a_v | 128-895 b_q | 896-1151 b_k
//             | 1152-1407 b_v | 1408-1535 zero pad
__global__ void pack_wt_k(const float* __restrict__ W0, const float* __restrict__ W1,
                          const float* __restrict__ W2, const float* __restrict__ W3,
                          const float* __restrict__ W4, const float* __restrict__ W5,
                          ushort* __restrict__ Wt) {
  __shared__ ushort tile[64 * 66];
  const int k0 = blockIdx.x * 64, c0 = blockIdx.y * 64;
  const int tid = threadIdx.x;
#pragma unroll
  for (int i = 0; i < 16; ++i) {
    int idx = tid + i * 256;
    int kl = idx >> 6, cl = idx & 63;
    int c = c0 + cl, k = k0 + kl;
    float v;
    if (c < 96)        v = W0[(size_t)k * 96  + c];
    else if (c < 112)  v = W1[(size_t)k * 16  + (c - 96)];
    else if (c < 128)  v = W2[(size_t)k * 16  + (c - 112)];
    else if (c < 896)  v = W3[(size_t)k * 768 + (c - 128)];
    else if (c < 1152) v = W4[(size_t)k * 256 + (c - 896)];
    else if (c < 1408) v = W5[(size_t)k * 256 + (c - 1152)];
    else               v = 0.0f;
    tile[cl * 66 + kl] = f2bf(v);
  }
  __syncthreads();
#pragma unroll
  for (int i = 0; i < 16; ++i) {
    int idx = tid + i * 256;
    int cl = idx >> 6, kl = idx & 63;
    Wt[(size_t)(c0 + cl) * 2048 + (k0 + kl)] = tile[cl * 66 + kl];
  }
}

// ---------- kernel 3: GEMM  Y[8192][1536] = Xbf[8192][2048] @ Wt[1536][2048]^T, bf16 out ----
// BM=128 x BN=192, BK=64, 512 threads (8 waves, 2x4), 2 LDS buffers (80 KB total)
// -> grid 64x8 = 512 blocks = exactly 2 blocks/CU (100% chip, cross-block TLP).
// Per K-tile: barrier; STAGE(t+1) (5 gloads); vmcnt(5) counted wait (tile t's loads,
// issued one full tile ago); barrier; then 2 phases x 12 MFMA with NO intra-tile
// barriers (reads of the same buf have no hazard).  Row = 64 elems = 128 B = 8
// 16B-chunks; chunk XOR-swizzled with (row&7) (bank-uniform by construction),
// pre-swizzled on the global source so gload_lds dests stay linear (rule 21).
__global__ __launch_bounds__(512, 4) void gemm_bt_k(const ushort* __restrict__ X,
                                                    const ushort* __restrict__ Wt,
                                                    ushort* __restrict__ Y) {
  extern __shared__ ushort lds[];                 // 2 bufs x 20480 ushorts (40 KB each)
  const int tid = threadIdx.x;
  const int wid = tid >> 6, lane = tid & 63;
  const int bid = blockIdx.x;
  // XCD-aware mapping: consecutive bids round-robin XCDs; give each XCD a bm-band
  // so its 8 bn-tiles share the X panel in XCD-L2.  Bijective: 512 = 8 xcd * 8 bm * 8 bn.
  const int xcd = bid & 7, i = bid >> 3;
  const int bm = xcd * 8 + (i >> 3);              // 0..63
  const int bn = i & 7;                           // 0..7
  const int wr = wid >> 2, wc = wid & 3;          // wave -> 64-row half, 48-col quarter

  // ---- staging sources (pre-swizzled): A 2 insts, B 3 insts per thread per K-tile ----
  const ushort* gA[2];
  const ushort* gB[3];
#pragma unroll
  for (int j = 0; j < 2; ++j) {
    int flat = j * 512 + tid;
    int r = flat >> 3, c = (flat & 7) ^ (r & 7);
    gA[j] = X + (size_t)(bm * 128 + r) * 2048 + c * 8;
  }
#pragma unroll
  for (int j = 0; j < 3; ++j) {
    int flat = j * 512 + tid;
    int r = flat >> 3, c = (flat & 7) ^ (r & 7);
    gB[j] = Wt + (size_t)(bn * 192 + r) * 2048 + c * 8;
  }

  // ---- fragment ds_read offsets (ushort units), swizzle-matched ----
  // A frag (m, kslot): row r = wr*64 + m*16 + (lane&15); chunk = (kk*4+(lane>>4)) ^ (r&7)
  int offA[4][2], offB[3][2];
#pragma unroll
  for (int m = 0; m < 4; ++m) {
    int r = wr * 64 + m * 16 + (lane & 15);
#pragma unroll
    for (int kk = 0; kk < 2; ++kk)
      offA[m][kk] = r * 64 + (((kk * 4 + (lane >> 4)) ^ (r & 7)) << 3);
  }
#pragma unroll
  for (int n = 0; n < 3; ++n) {
    int r = wc * 48 + n * 16 + (lane & 15);
#pragma unroll
    for (int kk = 0; kk < 2; ++kk)
      offB[n][kk] = 8192 + r * 64 + (((kk * 4 + (lane >> 4)) ^ (r & 7)) << 3);
  }

  f32x4 acc[4][3] = {};

#define STAGE(bi, kt) do { \
    char* _b = (char*)lds + (bi) * 40960; \
    const int _ko = (kt) * 64; \
    GLOAD_LDS16(gA[0] + _ko, _b + wid * 1024); \
    GLOAD_LDS16(gA[1] + _ko, _b + 8192 + wid * 1024); \
    GLOAD_LDS16(gB[0] + _ko, _b + 16384 + wid * 1024); \
    GLOAD_LDS16(gB[1] + _ko, _b + 24576 + wid * 1024); \
    GLOAD_LDS16(gB[2] + _ko, _b + 32768 + wid * 1024); \
  } while (0)
#define FRAG(off) (*reinterpret_cast<const bf16x8*>(cb + (off)))

  STAGE(0, 0);                                    // prologue: tile 0 -> buf 0

#pragma unroll 1
  for (int t = 0; t < 32; ++t) {
    asm volatile("s_barrier" ::: "memory");       // all waves done reading buf (t+1)&1
    if (t < 31) {
      STAGE((t + 1) & 1, t + 1);                  // issue next tile (5 insts)
      asm volatile("s_waitcnt vmcnt(5)" ::: "memory");   // retire tile t's 5 (1 tile of slack)
    } else {
      asm volatile("s_waitcnt vmcnt(0)" ::: "memory");   // tail drain
    }
    asm volatile("s_barrier" ::: "memory");       // tile t data visible to all waves

    const ushort* cb = lds + (t & 1) * 20480;
    // ---- phase 1: k-slot 0 ----
    {
      bf16x8 a0 = FRAG(offA[0][0]), a1 = FRAG(offA[1][0]),
             a2 = FRAG(offA[2][0]), a3 = FRAG(offA[3][0]);
      bf16x8 b0 = FRAG(offB[0][0]), b1 = FRAG(offB[1][0]), b2 = FRAG(offB[2][0]);
      __builtin_amdgcn_s_setprio(1);
#pragma unroll
      for (int n = 0; n < 3; ++n) {
        bf16x8 bb = (n == 0) ? b0 : (n == 1) ? b1 : b2;
        acc[0][n] = __builtin_amdgcn_mfma_f32_16x16x32_bf16(a0, bb, acc[0][n], 0, 0, 0);
        acc[1][n] = __builtin_amdgcn_mfma_f32_16x16x32_bf16(a1, bb, acc[1][n], 0, 0, 0);
        acc[2][n] = __builtin_amdgcn_mfma_f32_16x16x32_bf16(a2, bb, acc[2][n], 0, 0, 0);
        acc[3][n] = __builtin_amdgcn_mfma_f32_16x16x32_bf16(a3, bb, acc[3][n], 0, 0, 0);
      }
      __builtin_amdgcn_s_setprio(0);
    }
    // ---- phase 2: k-slot 1 (same buf, no barrier needed) ----
    {
      bf16x8 a0 = FRAG(offA[0][1]), a1 = FRAG(offA[1][1]),
             a2 = FRAG(offA[2][1]), a3 = FRAG(offA[3][1]);
      bf16x8 b0 = FRAG(offB[0][1]), b1 = FRAG(offB[1][1]), b2 = FRAG(offB[2][1]);
      __builtin_amdgcn_s_setprio(1);
#pragma unroll
      for (int n = 0; n < 3; ++n) {
        bf16x8 bb = (n == 0) ? b0 : (n == 1) ? b1 : b2;
        acc[0][n] = __builtin_amdgcn_mfma_f32_16x16x32_bf16(a0, bb, acc[0][n], 0, 0, 0);
        acc[1][n] = __builtin_amdgcn_mfma_f32_16x16x32_bf16(a1, bb, acc[1][n], 0, 0, 0);
        acc[2][n] = __builtin_amdgcn_mfma_f32_16x16x32_bf16(a2, bb, acc[2][n], 0, 0, 0);
        acc[3][n] = __builtin_amdgcn_mfma_f32_16x16x32_bf16(a3, bb, acc[3][n], 0, 0, 0);
      }
      __builtin_amdgcn_s_setprio(0);
    }
  }

#undef STAGE
#undef FRAG

  // epilogue: C/D layout col=lane&15, row=(lane>>4)*4+j  [m89-verified]; bf16 stores
#pragma unroll
  for (int m = 0; m < 4; ++m) {
    int row0 = bm * 128 + wr * 64 + m * 16 + ((lane >> 4) << 2);
#pragma unroll
    for (int n = 0; n < 3; ++n) {
      int col = bn * 192 + wc * 48 + n * 16 + (lane & 15);
#pragma unroll
      for (int j = 0; j < 4; ++j)
        Y[(size_t)(row0 + j) * 1536 + col] = f2bf(acc[m][n][j]);
    }
  }
}

// ---------- kernel 4: per-token low-rank reconstruction + concat (bf16 Y in, f32 out) ----
// Y row (stride 1536, first 1408 valid): [0,96) a_q | [96,112) a_k | [112,128) a_v
//   | [128,896) b_q | [896,1152) b_k | [1152,1408) b_v
// out row (4096): per group g: q_head(2g)[128] q_head(2g+1)[128] k_g[128] v_g[128]
__global__ void recon_k(const ushort* __restrict__ Y, float4* __restrict__ out) {
  __shared__ float L[1408];
  const int t = blockIdx.x, tid = threadIdx.x;
  const ushort* src = Y + (size_t)t * 1536;
  if (tid < 176) {                        // 176 x 16B = 1408 bf16
    ushort4 v0 = ((const ushort4*)src)[tid * 2];
    ushort4 v1 = ((const ushort4*)src)[tid * 2 + 1];
    float* d = L + tid * 8;
    d[0] = bf2f(v0.x); d[1] = bf2f(v0.y); d[2] = bf2f(v0.z); d[3] = bf2f(v0.w);
    d[4] = bf2f(v1.x); d[5] = bf2f(v1.y); d[6] = bf2f(v1.z); d[7] = bf2f(v1.w);
  }
  __syncthreads();
  float4* o = out + (size_t)t * 1024;
#pragma unroll
  for (int i = 0; i < 4; ++i) {
    int q4 = tid + (i << 8);              // float4 index 0..1023
    int p = q4 << 2;
    int g = p >> 9, sub = p & 511;
    float4 val;
    if (sub < 256) {                      // q
      int h = (g << 1) + (sub >> 7), d = sub & 127;
      const float* a = L + h * 6;
      const float* b = L + 128 + d;
#pragma unroll
      for (int c = 0; c < 4; ++c)
        (&val.x)[c] = (a[0] * b[c] + a[1] * b[128 + c] + a[2] * b[256 + c] +
                       a[3] * b[384 + c] + a[4] * b[512 + c] + a[5] * b[640 + c]) * (1.0f / 6.0f);
    } else if (sub < 384) {               // k
      int d = sub - 256;
      float a0 = L[96 + (g << 1)], a1 = L[97 + (g << 1)];
#pragma unroll
      for (int c = 0; c < 4; ++c)
        (&val.x)[c] = 0.5f * (a0 * L[896 + d + c] + a1 * L[1024 + d + c]);
    } else {                              // v
      int d = sub - 384;
      float a0 = L[112 + (g << 1)], a1 = L[113 + (g << 1)];
#pragma unroll
      for (int c = 0; c < 4; ++c)
        (&val.x)[c] = 0.5f * (a0 * L[1152 + d + c] + a1 * L[1280 + d + c]);
    }
    o[q4] = val;
  }
}

// ---------- launch ----------
extern "C" void kernel_launch(void* const* d_in, const int* in_sizes, int n_in,
                              void* d_out, int out_size, void* d_ws, size_t ws_size,
                              hipStream_t stream) {
  const float* x   = (const float*)d_in[0];
  const float* Waq = (const float*)d_in[1];
  const float* Wak = (const float*)d_in[2];
  const float* Wav = (const float*)d_in[3];
  const float* Wbq = (const float*)d_in[4];
  const float* Wbk = (const float*)d_in[5];
  const float* Wbv = (const float*)d_in[6];

  // workspace layout
  ushort* Xbf = (ushort*)d_ws;                                  // 8192*2048*2 = 33,554,432 B
  ushort* Wt  = (ushort*)((char*)d_ws + 33554432);              // 1536*2048*2 =  6,291,456 B
  ushort* Y   = (ushort*)((char*)d_ws + 39845888);              // 8192*1536*2 = 25,165,824 B
  float*  out = (float*)d_out;

  // allow 80 KB dynamic LDS for the gemm (idempotent; same call every launch)
  hipFuncSetAttribute(reinterpret_cast<const void*>(gemm_bt_k),
                      hipFuncAttributeMaxDynamicSharedMemorySize, 81920);

  cast_x_k<<<2048, 256, 0, stream>>>((const float4*)x, (ushort4*)Xbf, 16777216 / 4);
  pack_wt_k<<<dim3(32, 24), 256, 0, stream>>>(Waq, Wak, Wav, Wbq, Wbk, Wbv, Wt);
  gemm_bt_k<<<512, 512, 81920, stream>>>(Xbf, Wt, Y);
  recon_k<<<8192, 256, 0, stream>>>(Y, (float4*)out);
}